// Round 5
// baseline (547.903 us; speedup 1.0000x reference)
//
#include <hip/hip_runtime.h>

#define SEQ   2048
#define DD    2048   // H * Dh
#define DH    128
#define NH    16
#define QBLK  64
#define KVBLK 64
#define NT    (SEQ / KVBLK)

#define KSTR  136    // K lds row stride (bf16 elems): 64 rows x 128 cols padded
#define VSTR  68     // Vt lds row stride: 128 rows (d) x 64 cols (key) padded
#define PSTR  72     // P lds row stride: 16 rows x 64 cols padded

typedef __attribute__((ext_vector_type(8))) short bf16x8;
typedef __attribute__((ext_vector_type(4))) short bf16x4;
typedef __attribute__((ext_vector_type(4))) float f32x4;

__device__ __forceinline__ unsigned short f2bf(float f) {
    unsigned int u = __builtin_bit_cast(unsigned int, f);
    u += 0x7fffu + ((u >> 16) & 1u);          // round-to-nearest-even
    return (unsigned short)(u >> 16);
}

__device__ __forceinline__ bf16x8 pack8(const float4 a, const float4 b) {
    bf16x8 v;
    v[0] = (short)f2bf(a.x); v[1] = (short)f2bf(a.y);
    v[2] = (short)f2bf(a.z); v[3] = (short)f2bf(a.w);
    v[4] = (short)f2bf(b.x); v[5] = (short)f2bf(b.y);
    v[6] = (short)f2bf(b.z); v[7] = (short)f2bf(b.w);
    return v;
}

__global__ __launch_bounds__(256)
void fa_fwd(const float* __restrict__ qg, const float* __restrict__ kg,
            const float* __restrict__ vg, float* __restrict__ og) {
    __shared__ __align__(16) unsigned short Klds[KVBLK * KSTR];
    __shared__ __align__(16) unsigned short Vt[DH * VSTR];
    __shared__ __align__(16) unsigned short Plds[4 * 16 * PSTR];

    const int tid  = threadIdx.x;
    const int w    = tid >> 6;        // wave 0..3, owns q-rows w*16..w*16+15
    const int lane = tid & 63;
    const int lo   = lane & 15;
    const int hi   = lane >> 4;

    const int bid = blockIdx.x;
    const int qt  = bid & 31;         // S/QBLK = 32
    const int bh  = bid >> 5;
    const int b   = bh >> 4;
    const int h   = bh & 15;
    const int q0  = qt * QBLK;

    const size_t base = (size_t)b * SEQ * DD + (size_t)h * DH;

    // ---- Q fragments in registers (A-layout: row=lo, k = kc*32 + hi*8 + j) ----
    bf16x8 qf[4];
    {
        const float* qp = qg + base + (size_t)(q0 + w * 16 + lo) * DD + hi * 8;
        #pragma unroll
        for (int kc = 0; kc < 4; ++kc) {
            float4 a = *(const float4*)(qp + kc * 32);
            float4 c = *(const float4*)(qp + kc * 32 + 4);
            qf[kc] = pack8(a, c);
        }
    }

    f32x4 acco[8];
    const f32x4 zf = {0.f, 0.f, 0.f, 0.f};
    #pragma unroll
    for (int i = 0; i < 8; ++i) acco[i] = zf;
    float mrun[4] = {-1e30f, -1e30f, -1e30f, -1e30f};  // in log2 units
    float lrun[4] = {0.f, 0.f, 0.f, 0.f};

    // fold softmax scale and ln->log2 conversion: p = exp2(s*SCL - m2)
    const float SCL = 0.08838834764831843f * 1.4426950408889634f;

    unsigned short* pw = Plds + w * 16 * PSTR;

    for (int t = 0; t < NT; ++t) {
        const int k0 = t * KVBLK;
        __syncthreads();   // previous tile's LDS reads complete before overwrite

        // ---- stage K tile [64][128] fp32 -> bf16 row-major (padded) ----
        #pragma unroll
        for (int i = 0; i < 4; ++i) {
            int s   = tid + i * 256;      // 1024 slots of 8 elems
            int row = s >> 4;
            int c8  = s & 15;
            const float* p = kg + base + (size_t)(k0 + row) * DD + c8 * 8;
            float4 a = *(const float4*)p;
            float4 c = *(const float4*)(p + 4);
            *(bf16x8*)&Klds[row * KSTR + c8 * 8] = pack8(a, c);
        }
        // ---- stage V tile transposed: Vt[d][key], packed 2 keys per u32 ----
        #pragma unroll
        for (int i = 0; i < 4; ++i) {
            int s  = tid + i * 256;       // 1024 pairs
            int kp = s >> 5;              // key pair 0..31
            int c4 = s & 31;              // d = c4*4
            const float* p0 = vg + base + (size_t)(k0 + kp * 2) * DD + c4 * 4;
            float4 va = *(const float4*)p0;        // key kp*2,   d..d+3
            float4 vb = *(const float4*)(p0 + DD); // key kp*2+1, d..d+3
            unsigned int w0 = (unsigned)f2bf(va.x) | ((unsigned)f2bf(vb.x) << 16);
            unsigned int w1 = (unsigned)f2bf(va.y) | ((unsigned)f2bf(vb.y) << 16);
            unsigned int w2 = (unsigned)f2bf(va.z) | ((unsigned)f2bf(vb.z) << 16);
            unsigned int w3 = (unsigned)f2bf(va.w) | ((unsigned)f2bf(vb.w) << 16);
            unsigned short* vt0 = &Vt[(c4 * 4) * VSTR + kp * 2];
            *(unsigned int*)(vt0)            = w0;
            *(unsigned int*)(vt0 + VSTR)     = w1;
            *(unsigned int*)(vt0 + 2 * VSTR) = w2;
            *(unsigned int*)(vt0 + 3 * VSTR) = w3;
        }
        __syncthreads();

        // ---- S = Q K^T : C[qrow][key], qrow=(hi*4+r), key=nt*16+lo ----
        f32x4 accs[4];
        #pragma unroll
        for (int nt = 0; nt < 4; ++nt) accs[nt] = zf;
        #pragma unroll
        for (int nt = 0; nt < 4; ++nt) {
            #pragma unroll
            for (int kk = 0; kk < 4; ++kk) {
                bf16x8 kb = *(const bf16x8*)&Klds[(nt * 16 + lo) * KSTR + kk * 32 + hi * 8];
                accs[nt] = __builtin_amdgcn_mfma_f32_16x16x32_bf16(qf[kk], kb, accs[nt], 0, 0, 0);
            }
        }

        // ---- online softmax (log2 domain), per q-row r, reduce across lo ----
        float ps[4][4];
        float corr[4];
        #pragma unroll
        for (int r = 0; r < 4; ++r) {
            float s0 = accs[0][r] * SCL, s1 = accs[1][r] * SCL;
            float s2 = accs[2][r] * SCL, s3 = accs[3][r] * SCL;
            float tm = fmaxf(fmaxf(s0, s1), fmaxf(s2, s3));
            tm = fmaxf(tm, __shfl_xor(tm, 1));
            tm = fmaxf(tm, __shfl_xor(tm, 2));
            tm = fmaxf(tm, __shfl_xor(tm, 4));
            tm = fmaxf(tm, __shfl_xor(tm, 8));
            float mn = fmaxf(mrun[r], tm);
            float c  = exp2f(mrun[r] - mn);
            float p0 = exp2f(s0 - mn), p1 = exp2f(s1 - mn);
            float p2 = exp2f(s2 - mn), p3 = exp2f(s3 - mn);
            float ls = p0 + p1 + p2 + p3;
            ls += __shfl_xor(ls, 1);
            ls += __shfl_xor(ls, 2);
            ls += __shfl_xor(ls, 4);
            ls += __shfl_xor(ls, 8);
            lrun[r] = lrun[r] * c + ls;
            mrun[r] = mn;
            corr[r] = c;
            ps[0][r] = p0; ps[1][r] = p1; ps[2][r] = p2; ps[3][r] = p3;
        }
        #pragma unroll
        for (int d0 = 0; d0 < 8; ++d0) {
            acco[d0][0] *= corr[0]; acco[d0][1] *= corr[1];
            acco[d0][2] *= corr[2]; acco[d0][3] *= corr[3];
        }

        // ---- P: C-layout -> LDS -> A-layout (wave-private, no barrier) ----
        #pragma unroll
        for (int nt = 0; nt < 4; ++nt)
            #pragma unroll
            for (int r = 0; r < 4; ++r)
                pw[(hi * 4 + r) * PSTR + nt * 16 + lo] = f2bf(ps[nt][r]);

        // ---- O += P V : A = P[16 x 64], B = V[64 x 128] via Vt ----
        #pragma unroll
        for (int kc = 0; kc < 2; ++kc) {
            bf16x8 pa = *(const bf16x8*)&pw[lo * PSTR + kc * 32 + hi * 8];
            #pragma unroll
            for (int d0 = 0; d0 < 8; ++d0) {
                const unsigned short* vp = &Vt[(d0 * 16 + lo) * VSTR + kc * 32 + hi * 8];
                bf16x4 v0 = *(const bf16x4*)vp;
                bf16x4 v1 = *(const bf16x4*)(vp + 4);
                bf16x8 vb = __builtin_shufflevector(v0, v1, 0, 1, 2, 3, 4, 5, 6, 7);
                acco[d0] = __builtin_amdgcn_mfma_f32_16x16x32_bf16(pa, vb, acco[d0], 0, 0, 0);
            }
        }
    }

    // ---- epilogue: normalize and store fp32 ----
    float inv[4];
    #pragma unroll
    for (int r = 0; r < 4; ++r) inv[r] = 1.0f / lrun[r];
    float* op = og + base + (size_t)(q0 + w * 16 + hi * 4) * DD + lo;
    #pragma unroll
    for (int d0 = 0; d0 < 8; ++d0)
        #pragma unroll
        for (int r = 0; r < 4; ++r)
            op[(size_t)r * DD + d0 * 16] = acco[d0][r] * inv[r];
}

extern "C" void kernel_launch(void* const* d_in, const int* in_sizes, int n_in,
                              void* d_out, int out_size, void* d_ws, size_t ws_size,
                              hipStream_t stream) {
    const float* q = (const float*)d_in[0];
    const float* k = (const float*)d_in[1];
    const float* v = (const float*)d_in[2];
    float* o = (float*)d_out;
    const int B = in_sizes[0] / (SEQ * DD);
    dim3 grid(B * NH * (SEQ / QBLK));
    fa_fwd<<<grid, dim3(256), 0, stream>>>(q, k, v, o);
}

// Round 7
// 361.721 us; speedup vs baseline: 1.5147x; 1.5147x over previous
//
#include <hip/hip_runtime.h>

#define SEQ   2048
#define DD    2048   // H * Dh
#define DH    128
#define NH    16
#define QBLK  128
#define KVBLK 64
#define NT    (SEQ / KVBLK)
#define NWAVE 8
#define BLK   (NWAVE * 64)

#define KSTR  136    // K lds row stride (bf16 elems): 64 rows x 128 cols padded
#define VSTR  68     // Vt lds row stride: 128 rows (d) x 64 cols (key) padded
#define PSTR  72     // P lds row stride: 16 rows x 64 cols padded

typedef __attribute__((ext_vector_type(8))) short bf16x8;
typedef __attribute__((ext_vector_type(4))) short bf16x4;
typedef __attribute__((ext_vector_type(4))) float f32x4;

__device__ __forceinline__ unsigned short f2bf(float f) {
    unsigned int u = __builtin_bit_cast(unsigned int, f);
    u += 0x7fffu + ((u >> 16) & 1u);          // round-to-nearest-even
    return (unsigned short)(u >> 16);
}

__device__ __forceinline__ bf16x8 pack8(const float4 a, const float4 b) {
    bf16x8 v;
    v[0] = (short)f2bf(a.x); v[1] = (short)f2bf(a.y);
    v[2] = (short)f2bf(a.z); v[3] = (short)f2bf(a.w);
    v[4] = (short)f2bf(b.x); v[5] = (short)f2bf(b.y);
    v[6] = (short)f2bf(b.z); v[7] = (short)f2bf(b.w);
    return v;
}

__global__ __launch_bounds__(BLK, 4)
void fa_fwd(const float* __restrict__ qg, const float* __restrict__ kg,
            const float* __restrict__ vg, float* __restrict__ og) {
    __shared__ __align__(16) unsigned short Klds[KVBLK * KSTR];   // 17408 B
    __shared__ __align__(16) unsigned short Vt[DH * VSTR];        // 17408 B
    __shared__ __align__(16) unsigned short Plds[NWAVE * 16 * PSTR]; // 18432 B

    const int tid  = threadIdx.x;
    const int w    = tid >> 6;        // wave 0..7, owns q-rows w*16..w*16+15
    const int lane = tid & 63;
    const int lo   = lane & 15;
    const int hi   = lane >> 4;

    const int bid = blockIdx.x;
    const int qt  = bid & 15;         // S/QBLK = 16
    const int bh  = bid >> 4;
    const int b   = bh >> 4;
    const int h   = bh & 15;
    const int q0  = qt * QBLK;

    const size_t base = (size_t)b * SEQ * DD + (size_t)h * DH;

    // ---- Q fragments in registers (A-layout: row=lo, k = kc*32 + hi*8 + j) ----
    bf16x8 qf[4];
    {
        const float* qp = qg + base + (size_t)(q0 + w * 16 + lo) * DD + hi * 8;
        #pragma unroll
        for (int kc = 0; kc < 4; ++kc) {
            float4 a = *(const float4*)(qp + kc * 32);
            float4 c = *(const float4*)(qp + kc * 32 + 4);
            qf[kc] = pack8(a, c);
        }
    }

    f32x4 acco[8];
    const f32x4 zf = {0.f, 0.f, 0.f, 0.f};
    #pragma unroll
    for (int i = 0; i < 8; ++i) acco[i] = zf;
    float mrun[4] = {-1e30f, -1e30f, -1e30f, -1e30f};  // in log2 units
    float lrun[4] = {0.f, 0.f, 0.f, 0.f};

    // fold softmax scale and ln->log2 conversion: p = exp2(s*SCL - m2)
    const float SCL = 0.08838834764831843f * 1.4426950408889634f;

    unsigned short* pw = Plds + w * 16 * PSTR;

    // ---- prefetch registers: tile t+1's raw fp32 (issue-early / write-late) ----
    float4 kra[2], krc[2], vra[2], vrb[2];

    // K: slot s covers row=s>>4 (0..63), c8=s&15 (8 floats each); 1024 slots / 512 thr
    // V: slot s covers key-pair kp=s>>5 (0..31), c4=s&31 (d = c4*4); 1024 slots
    #define LOADT(T)                                                            \
        {                                                                       \
            const int k0_ = (T) * KVBLK;                                        \
            _Pragma("unroll")                                                   \
            for (int i = 0; i < 2; ++i) {                                       \
                int s = tid + i * BLK;                                          \
                const float* p = kg + base + (size_t)(k0_ + (s >> 4)) * DD + (s & 15) * 8; \
                kra[i] = *(const float4*)p;                                     \
                krc[i] = *(const float4*)(p + 4);                               \
                const float* pv = vg + base + (size_t)(k0_ + (s >> 5) * 2) * DD + (s & 31) * 4; \
                vra[i] = *(const float4*)pv;                                    \
                vrb[i] = *(const float4*)(pv + DD);                             \
            }                                                                   \
        }

    LOADT(0);

    for (int t = 0; t < NT; ++t) {
        __syncthreads();   // previous tile's LDS reads complete before overwrite

        // ---- stage_write: convert prefetched regs -> LDS ----
        #pragma unroll
        for (int i = 0; i < 2; ++i) {
            int s = tid + i * BLK;
            *(bf16x8*)&Klds[(s >> 4) * KSTR + (s & 15) * 8] = pack8(kra[i], krc[i]);
        }
        #pragma unroll
        for (int i = 0; i < 2; ++i) {
            int s  = tid + i * BLK;
            int kp = s >> 5;
            int c4 = s & 31;
            unsigned int w0 = (unsigned)f2bf(vra[i].x) | ((unsigned)f2bf(vrb[i].x) << 16);
            unsigned int w1 = (unsigned)f2bf(vra[i].y) | ((unsigned)f2bf(vrb[i].y) << 16);
            unsigned int w2 = (unsigned)f2bf(vra[i].z) | ((unsigned)f2bf(vrb[i].z) << 16);
            unsigned int w3 = (unsigned)f2bf(vra[i].w) | ((unsigned)f2bf(vrb[i].w) << 16);
            unsigned short* vt0 = &Vt[(c4 * 4) * VSTR + kp * 2];
            *(unsigned int*)(vt0)            = w0;
            *(unsigned int*)(vt0 + VSTR)     = w1;
            *(unsigned int*)(vt0 + 2 * VSTR) = w2;
            *(unsigned int*)(vt0 + 3 * VSTR) = w3;
        }

        // ---- issue next tile's global loads; consumed after next barrier+compute ----
        if (t + 1 < NT) LOADT(t + 1);

        __syncthreads();

        // ---- S = Q K^T : C[qrow][key], qrow=(hi*4+r), key=nt*16+lo ----
        f32x4 accs[4];
        #pragma unroll
        for (int nt = 0; nt < 4; ++nt) accs[nt] = zf;
        #pragma unroll
        for (int nt = 0; nt < 4; ++nt) {
            #pragma unroll
            for (int kk = 0; kk < 4; ++kk) {
                bf16x8 kb = *(const bf16x8*)&Klds[(nt * 16 + lo) * KSTR + kk * 32 + hi * 8];
                accs[nt] = __builtin_amdgcn_mfma_f32_16x16x32_bf16(qf[kk], kb, accs[nt], 0, 0, 0);
            }
        }

        // ---- online softmax (log2 domain), per q-row r, reduce across lo ----
        float ps[4][4];
        float corr[4];
        #pragma unroll
        for (int r = 0; r < 4; ++r) {
            float s0 = accs[0][r] * SCL, s1 = accs[1][r] * SCL;
            float s2 = accs[2][r] * SCL, s3 = accs[3][r] * SCL;
            float tm = fmaxf(fmaxf(s0, s1), fmaxf(s2, s3));
            tm = fmaxf(tm, __shfl_xor(tm, 1));
            tm = fmaxf(tm, __shfl_xor(tm, 2));
            tm = fmaxf(tm, __shfl_xor(tm, 4));
            tm = fmaxf(tm, __shfl_xor(tm, 8));
            float mn = fmaxf(mrun[r], tm);
            float c  = exp2f(mrun[r] - mn);
            float p0 = exp2f(s0 - mn), p1 = exp2f(s1 - mn);
            float p2 = exp2f(s2 - mn), p3 = exp2f(s3 - mn);
            float ls = p0 + p1 + p2 + p3;
            ls += __shfl_xor(ls, 1);
            ls += __shfl_xor(ls, 2);
            ls += __shfl_xor(ls, 4);
            ls += __shfl_xor(ls, 8);
            lrun[r] = lrun[r] * c + ls;
            mrun[r] = mn;
            corr[r] = c;
            ps[0][r] = p0; ps[1][r] = p1; ps[2][r] = p2; ps[3][r] = p3;
        }
        #pragma unroll
        for (int d0 = 0; d0 < 8; ++d0) {
            acco[d0][0] *= corr[0]; acco[d0][1] *= corr[1];
            acco[d0][2] *= corr[2]; acco[d0][3] *= corr[3];
        }

        // ---- P: C-layout -> LDS -> A-layout (wave-private, no barrier) ----
        #pragma unroll
        for (int nt = 0; nt < 4; ++nt)
            #pragma unroll
            for (int r = 0; r < 4; ++r)
                pw[(hi * 4 + r) * PSTR + nt * 16 + lo] = f2bf(ps[nt][r]);

        // ---- O += P V : A = P[16 x 64], B = V[64 x 128] via Vt ----
        #pragma unroll
        for (int kc = 0; kc < 2; ++kc) {
            bf16x8 pa = *(const bf16x8*)&pw[lo * PSTR + kc * 32 + hi * 8];
            #pragma unroll
            for (int d0 = 0; d0 < 8; ++d0) {
                const unsigned short* vp = &Vt[(d0 * 16 + lo) * VSTR + kc * 32 + hi * 8];
                bf16x4 v0 = *(const bf16x4*)vp;
                bf16x4 v1 = *(const bf16x4*)(vp + 4);
                bf16x8 vb = __builtin_shufflevector(v0, v1, 0, 1, 2, 3, 4, 5, 6, 7);
                acco[d0] = __builtin_amdgcn_mfma_f32_16x16x32_bf16(pa, vb, acco[d0], 0, 0, 0);
            }
        }
    }

    // ---- epilogue: normalize and store fp32 ----
    float inv[4];
    #pragma unroll
    for (int r = 0; r < 4; ++r) inv[r] = 1.0f / lrun[r];
    float* op = og + base + (size_t)(q0 + w * 16 + hi * 4) * DD + lo;
    #pragma unroll
    for (int d0 = 0; d0 < 8; ++d0)
        #pragma unroll
        for (int r = 0; r < 4; ++r)
            op[(size_t)r * DD + d0 * 16] = acco[d0][r] * inv[r];
}

extern "C" void kernel_launch(void* const* d_in, const int* in_sizes, int n_in,
                              void* d_out, int out_size, void* d_ws, size_t ws_size,
                              hipStream_t stream) {
    const float* q = (const float*)d_in[0];
    const float* k = (const float*)d_in[1];
    const float* v = (const float*)d_in[2];
    float* o = (float*)d_out;
    const int B = in_sizes[0] / (SEQ * DD);
    dim3 grid(B * NH * (SEQ / QBLK));
    fa_fwd<<<grid, dim3(BLK), 0, stream>>>(q, k, v, o);
}

// Round 11
// 338.736 us; speedup vs baseline: 1.6175x; 1.0679x over previous
//
#include <hip/hip_runtime.h>
#include <hip/hip_bf16.h>

#define SEQ   2048
#define DD    2048   // H * Dh
#define DH    128
#define NH    16
#define QBLK  128
#define KVBLK 64
#define NT    (SEQ / KVBLK)
#define NWAVE 8
#define BLK   (NWAVE * 64)

#define KSTR  136    // K lds row stride (bf16 elems): 64 rows x 128 cols padded
#define VSTR  68     // Vt lds row stride: 128 rows (d) x 64 cols (key) padded
#define PSTR  72     // P lds row stride: 16 rows x 64 cols padded

typedef __attribute__((ext_vector_type(8))) short bf16x8;
typedef __attribute__((ext_vector_type(4))) short bf16x4;
typedef __attribute__((ext_vector_type(4))) float f32x4;
typedef __attribute__((ext_vector_type(4))) unsigned int u32x4;

// one v_cvt_pk_bf16_f32 (RNE) per pair — compiler pattern-matches this form
__device__ __forceinline__ unsigned int cvt2(float lo, float hi) {
    __hip_bfloat162 h = __float22bfloat162_rn(make_float2(lo, hi));
    unsigned int u;
    __builtin_memcpy(&u, &h, 4);      // folds to a register move
    return u;
}

__device__ __forceinline__ u32x4 pack8(const float4 a, const float4 b) {
    u32x4 v;
    v[0] = cvt2(a.x, a.y);
    v[1] = cvt2(a.z, a.w);
    v[2] = cvt2(b.x, b.y);
    v[3] = cvt2(b.z, b.w);
    return v;
}

__device__ __forceinline__ unsigned short f2bf1(float f) {
    __hip_bfloat16 h = __float2bfloat16(f);
    unsigned short u;
    __builtin_memcpy(&u, &h, 2);
    return u;
}

__global__ __launch_bounds__(BLK, 4)
void fa_fwd(const float* __restrict__ qg, const float* __restrict__ kg,
            const float* __restrict__ vg, float* __restrict__ og) {
    __shared__ __align__(16) unsigned short Klds[KVBLK * KSTR];   // 17408 B
    __shared__ __align__(16) unsigned short Vt[DH * VSTR];        // 17408 B
    __shared__ __align__(16) unsigned short Plds[NWAVE * 16 * PSTR]; // 18432 B

    const int tid  = threadIdx.x;
    const int w    = tid >> 6;        // wave 0..7, owns q-rows w*16..w*16+15
    const int lane = tid & 63;
    const int lo   = lane & 15;
    const int hi   = lane >> 4;

    const int bid = blockIdx.x;
    const int qt  = bid & 15;         // S/QBLK = 16
    const int bh  = bid >> 4;
    const int b   = bh >> 4;
    const int h   = bh & 15;
    const int q0  = qt * QBLK;

    const size_t base = (size_t)b * SEQ * DD + (size_t)h * DH;

    // ---- Q fragments in registers (A-layout: row=lo, k = kc*32 + hi*8 + j) ----
    bf16x8 qf[4];
    {
        const float* qp = qg + base + (size_t)(q0 + w * 16 + lo) * DD + hi * 8;
        #pragma unroll
        for (int kc = 0; kc < 4; ++kc) {
            float4 a = *(const float4*)(qp + kc * 32);
            float4 c = *(const float4*)(qp + kc * 32 + 4);
            qf[kc] = __builtin_bit_cast(bf16x8, pack8(a, c));
        }
    }

    f32x4 acco[8];
    const f32x4 zf = {0.f, 0.f, 0.f, 0.f};
    #pragma unroll
    for (int i = 0; i < 8; ++i) acco[i] = zf;
    float mrun[4] = {-1e30f, -1e30f, -1e30f, -1e30f};  // in log2 units
    float lrun[4] = {0.f, 0.f, 0.f, 0.f};

    // fold softmax scale and ln->log2 conversion: p = exp2(s*SCL - m2)
    const float SCL = 0.08838834764831843f * 1.4426950408889634f;

    unsigned short* pw = Plds + w * 16 * PSTR;

    // ---- prefetch registers: tile t+1's raw fp32 (issue-early / write-late) ----
    float4 kra[2], krc[2], vra[2], vrb[2];

    // K: slot s covers row=s>>4 (0..63), c8=s&15 (8 floats each); 1024 slots / 512 thr
    // V: slot s covers key-pair kp=s>>5 (0..31), c4=s&31 (d = c4*4); 1024 slots
    #define LOADT(T)                                                            \
        {                                                                       \
            const int k0_ = (T) * KVBLK;                                        \
            _Pragma("unroll")                                                   \
            for (int i = 0; i < 2; ++i) {                                       \
                int s = tid + i * BLK;                                          \
                const float* p = kg + base + (size_t)(k0_ + (s >> 4)) * DD + (s & 15) * 8; \
                kra[i] = *(const float4*)p;                                     \
                krc[i] = *(const float4*)(p + 4);                               \
                const float* pv = vg + base + (size_t)(k0_ + (s >> 5) * 2) * DD + (s & 31) * 4; \
                vra[i] = *(const float4*)pv;                                    \
                vrb[i] = *(const float4*)(pv + DD);                             \
            }                                                                   \
        }

    LOADT(0);

    for (int t = 0; t < NT; ++t) {
        __syncthreads();   // previous tile's LDS reads complete before overwrite

        // ---- stage_write: convert prefetched regs -> LDS ----
        #pragma unroll
        for (int i = 0; i < 2; ++i) {
            int s = tid + i * BLK;
            *(u32x4*)&Klds[(s >> 4) * KSTR + (s & 15) * 8] = pack8(kra[i], krc[i]);
        }
        #pragma unroll
        for (int i = 0; i < 2; ++i) {
            int s  = tid + i * BLK;
            int kp = s >> 5;
            int c4 = s & 31;
            unsigned int w0 = cvt2(vra[i].x, vrb[i].x);
            unsigned int w1 = cvt2(vra[i].y, vrb[i].y);
            unsigned int w2 = cvt2(vra[i].z, vrb[i].z);
            unsigned int w3 = cvt2(vra[i].w, vrb[i].w);
            unsigned short* vt0 = &Vt[(c4 * 4) * VSTR + kp * 2];
            *(unsigned int*)(vt0)            = w0;
            *(unsigned int*)(vt0 + VSTR)     = w1;
            *(unsigned int*)(vt0 + 2 * VSTR) = w2;
            *(unsigned int*)(vt0 + 3 * VSTR) = w3;
        }

        // ---- issue next tile's global loads; consumed after next barrier+compute ----
        if (t + 1 < NT) LOADT(t + 1);

        __syncthreads();

        // ---- S = Q K^T : C[qrow][key], qrow=(hi*4+r), key=nt*16+lo ----
        f32x4 accs[4];
        #pragma unroll
        for (int nt = 0; nt < 4; ++nt) accs[nt] = zf;
        #pragma unroll
        for (int nt = 0; nt < 4; ++nt) {
            #pragma unroll
            for (int kk = 0; kk < 4; ++kk) {
                bf16x8 kb = *(const bf16x8*)&Klds[(nt * 16 + lo) * KSTR + kk * 32 + hi * 8];
                accs[nt] = __builtin_amdgcn_mfma_f32_16x16x32_bf16(qf[kk], kb, accs[nt], 0, 0, 0);
            }
        }

        // ---- online softmax (log2 domain), per q-row r, reduce across lo ----
        float ps[4][4];
        float corr[4];
        #pragma unroll
        for (int r = 0; r < 4; ++r) {
            float s0 = accs[0][r] * SCL, s1 = accs[1][r] * SCL;
            float s2 = accs[2][r] * SCL, s3 = accs[3][r] * SCL;
            float tm = fmaxf(fmaxf(s0, s1), fmaxf(s2, s3));
            tm = fmaxf(tm, __shfl_xor(tm, 1));
            tm = fmaxf(tm, __shfl_xor(tm, 2));
            tm = fmaxf(tm, __shfl_xor(tm, 4));
            tm = fmaxf(tm, __shfl_xor(tm, 8));
            float mn = fmaxf(mrun[r], tm);
            float c  = exp2f(mrun[r] - mn);
            float p0 = exp2f(s0 - mn), p1 = exp2f(s1 - mn);
            float p2 = exp2f(s2 - mn), p3 = exp2f(s3 - mn);
            float ls = p0 + p1 + p2 + p3;
            ls += __shfl_xor(ls, 1);
            ls += __shfl_xor(ls, 2);
            ls += __shfl_xor(ls, 4);
            ls += __shfl_xor(ls, 8);
            lrun[r] = lrun[r] * c + ls;
            mrun[r] = mn;
            corr[r] = c;
            ps[0][r] = p0; ps[1][r] = p1; ps[2][r] = p2; ps[3][r] = p3;
        }
        #pragma unroll
        for (int d0 = 0; d0 < 8; ++d0) {
            acco[d0][0] *= corr[0]; acco[d0][1] *= corr[1];
            acco[d0][2] *= corr[2]; acco[d0][3] *= corr[3];
        }

        // ---- P: C-layout -> LDS -> A-layout (wave-private, no barrier) ----
        #pragma unroll
        for (int nt = 0; nt < 4; ++nt)
            #pragma unroll
            for (int r = 0; r < 4; ++r)
                pw[(hi * 4 + r) * PSTR + nt * 16 + lo] = f2bf1(ps[nt][r]);

        // ---- O += P V : A = P[16 x 64], B = V[64 x 128] via Vt ----
        #pragma unroll
        for (int kc = 0; kc < 2; ++kc) {
            bf16x8 pa = *(const bf16x8*)&pw[lo * PSTR + kc * 32 + hi * 8];
            #pragma unroll
            for (int d0 = 0; d0 < 8; ++d0) {
                const unsigned short* vp = &Vt[(d0 * 16 + lo) * VSTR + kc * 32 + hi * 8];
                bf16x4 v0 = *(const bf16x4*)vp;
                bf16x4 v1 = *(const bf16x4*)(vp + 4);
                bf16x8 vb = __builtin_shufflevector(v0, v1, 0, 1, 2, 3, 4, 5, 6, 7);
                acco[d0] = __builtin_amdgcn_mfma_f32_16x16x32_bf16(pa, vb, acco[d0], 0, 0, 0);
            }
        }
    }

    // ---- epilogue: normalize and store fp32 ----
    float inv[4];
    #pragma unroll
    for (int r = 0; r < 4; ++r) inv[r] = 1.0f / lrun[r];
    float* op = og + base + (size_t)(q0 + w * 16 + hi * 4) * DD + lo;
    #pragma unroll
    for (int d0 = 0; d0 < 8; ++d0)
        #pragma unroll
        for (int r = 0; r < 4; ++r)
            op[(size_t)r * DD + d0 * 16] = acco[d0][r] * inv[r];
}

extern "C" void kernel_launch(void* const* d_in, const int* in_sizes, int n_in,
                              void* d_out, int out_size, void* d_ws, size_t ws_size,
                              hipStream_t stream) {
    const float* q = (const float*)d_in[0];
    const float* k = (const float*)d_in[1];
    const float* v = (const float*)d_in[2];
    float* o = (float*)d_out;
    const int B = in_sizes[0] / (SEQ * DD);
    dim3 grid(B * NH * (SEQ / QBLK));
    fa_fwd<<<grid, dim3(BLK), 0, stream>>>(q, k, v, o);
}